// Round 2
// baseline (415.529 us; speedup 1.0000x reference)
//
#include <hip/hip_runtime.h>
#include <hip/hip_bf16.h>

// Problem constants: B=2, N=64, D=256, H=8, DK=32. All I/O fp32.
#define ROWS 8192          // B*N*N
#define DIM  256

// ---------------------------------------------------------------------------
// Projection GEMM: C_w = x(8192x256) @ W_w(256x256), w in {lk,rk,lv,rv}
// out = outbase + w*ROWS*DIM. 64x64 tile, BK=32, 256 thr, 4x4 micro.
// grid = (16 n-tiles, 128 m-tiles)
// ---------------------------------------------------------------------------
__global__ __launch_bounds__(256)
void proj_gemm(const float* __restrict__ x,
               const float* __restrict__ W0,
               const float* __restrict__ W1,
               const float* __restrict__ W2,
               const float* __restrict__ W3,
               float* __restrict__ outbase)
{
    __shared__ float As[32][65];
    __shared__ float Bs[32][65];
    const int nt = blockIdx.x, mt = blockIdx.y;
    const int wsel = nt >> 2;
    const float* __restrict__ W = (wsel == 0) ? W0 : (wsel == 1) ? W1 : (wsel == 2) ? W2 : W3;
    float* __restrict__ out = outbase + (size_t)wsel * (ROWS * DIM);
    const int col0 = (nt & 3) * 64;
    const int m0g = mt * 64;
    const int tid = threadIdx.x;
    const int lm = tid >> 2, lk0 = (tid & 3) * 8;   // A-tile: 64 rows x 32 k
    const int bk = tid >> 3, bn = (tid & 7) * 8;    // B-tile: 32 k x 64 cols
    const int m0 = (tid >> 4) * 4, n0 = (tid & 15) * 4;
    float acc[4][4] = {};

    for (int k0 = 0; k0 < 256; k0 += 32) {
        const float* ap = x + (size_t)(m0g + lm) * 256 + k0 + lk0;
        float4 a0 = *(const float4*)(ap);
        float4 a1 = *(const float4*)(ap + 4);
        As[lk0 + 0][lm] = a0.x; As[lk0 + 1][lm] = a0.y;
        As[lk0 + 2][lm] = a0.z; As[lk0 + 3][lm] = a0.w;
        As[lk0 + 4][lm] = a1.x; As[lk0 + 5][lm] = a1.y;
        As[lk0 + 6][lm] = a1.z; As[lk0 + 7][lm] = a1.w;
        const float* bp = W + (size_t)(k0 + bk) * 256 + col0 + bn;
        float4 b0 = *(const float4*)(bp);
        float4 b1 = *(const float4*)(bp + 4);
        Bs[bk][bn + 0] = b0.x; Bs[bk][bn + 1] = b0.y;
        Bs[bk][bn + 2] = b0.z; Bs[bk][bn + 3] = b0.w;
        Bs[bk][bn + 4] = b1.x; Bs[bk][bn + 5] = b1.y;
        Bs[bk][bn + 6] = b1.z; Bs[bk][bn + 7] = b1.w;
        __syncthreads();
        #pragma unroll
        for (int kk = 0; kk < 32; ++kk) {
            float av[4], bv[4];
            #pragma unroll
            for (int i = 0; i < 4; ++i) av[i] = As[kk][m0 + i];
            #pragma unroll
            for (int j = 0; j < 4; ++j) bv[j] = Bs[kk][n0 + j];
            #pragma unroll
            for (int i = 0; i < 4; ++i)
                #pragma unroll
                for (int j = 0; j < 4; ++j)
                    acc[i][j] += av[i] * bv[j];
        }
        __syncthreads();
    }
    #pragma unroll
    for (int i = 0; i < 4; ++i)
        #pragma unroll
        for (int j = 0; j < 4; ++j)
            out[(size_t)(m0g + m0 + i) * 256 + col0 + n0 + j] = acc[i][j];
}

// ---------------------------------------------------------------------------
// Generic GEMM: out = [relu]( A(8192xK) @ W(KxN) + bias ), all fp32
// grid = (N/64, 128)
// ---------------------------------------------------------------------------
__global__ __launch_bounds__(256)
void gemm_f32(const float* __restrict__ A, const float* __restrict__ W,
              const float* __restrict__ bias, int relu,
              float* __restrict__ out, int K, int N)
{
    __shared__ float As[32][65];
    __shared__ float Bs[32][65];
    const int col0 = blockIdx.x * 64;
    const int m0g = blockIdx.y * 64;
    const int tid = threadIdx.x;
    const int lm = tid >> 2, lk0 = (tid & 3) * 8;
    const int bk = tid >> 3, bn = (tid & 7) * 8;
    const int m0 = (tid >> 4) * 4, n0 = (tid & 15) * 4;
    float acc[4][4] = {};

    for (int k0 = 0; k0 < K; k0 += 32) {
        const float* ap = A + (size_t)(m0g + lm) * K + k0 + lk0;
        float4 a0 = *(const float4*)(ap);
        float4 a1 = *(const float4*)(ap + 4);
        As[lk0 + 0][lm] = a0.x; As[lk0 + 1][lm] = a0.y;
        As[lk0 + 2][lm] = a0.z; As[lk0 + 3][lm] = a0.w;
        As[lk0 + 4][lm] = a1.x; As[lk0 + 5][lm] = a1.y;
        As[lk0 + 6][lm] = a1.z; As[lk0 + 7][lm] = a1.w;
        const float* bp = W + (size_t)(k0 + bk) * N + col0 + bn;
        float4 b0 = *(const float4*)(bp);
        float4 b1 = *(const float4*)(bp + 4);
        Bs[bk][bn + 0] = b0.x; Bs[bk][bn + 1] = b0.y;
        Bs[bk][bn + 2] = b0.z; Bs[bk][bn + 3] = b0.w;
        Bs[bk][bn + 4] = b1.x; Bs[bk][bn + 5] = b1.y;
        Bs[bk][bn + 6] = b1.z; Bs[bk][bn + 7] = b1.w;
        __syncthreads();
        #pragma unroll
        for (int kk = 0; kk < 32; ++kk) {
            float av[4], bv[4];
            #pragma unroll
            for (int i = 0; i < 4; ++i) av[i] = As[kk][m0 + i];
            #pragma unroll
            for (int j = 0; j < 4; ++j) bv[j] = Bs[kk][n0 + j];
            #pragma unroll
            for (int i = 0; i < 4; ++i)
                #pragma unroll
                for (int j = 0; j < 4; ++j)
                    acc[i][j] += av[i] * bv[j];
        }
        __syncthreads();
    }
    float bb[4] = {0.f, 0.f, 0.f, 0.f};
    if (bias) {
        #pragma unroll
        for (int j = 0; j < 4; ++j) bb[j] = bias[col0 + n0 + j];
    }
    #pragma unroll
    for (int i = 0; i < 4; ++i)
        #pragma unroll
        for (int j = 0; j < 4; ++j) {
            float v = acc[i][j] + bb[j];
            if (relu) v = fmaxf(v, 0.f);
            out[(size_t)(m0g + m0 + i) * N + col0 + n0 + j] = v;
        }
}

// ---------------------------------------------------------------------------
// Triangle attention, one block per (b, h, x):
//   S[a,y] = sum_d lk[b,x,a,h,d]*rk[b,a,y,h,d] / sqrt(32)
//   att    = softmax_a(S)
//   o[y,d] = sum_a att[a,y]*lv[b,x,a,h,d]*rv[b,a,y,h,d]
// grid = (64 x, 8 h, 2 b), 256 threads
// ---------------------------------------------------------------------------
__global__ __launch_bounds__(256)
void tri_attn(const float* __restrict__ lk, const float* __restrict__ rk,
              const float* __restrict__ lv, const float* __restrict__ rv,
              float* __restrict__ obuf)
{
    __shared__ float lkx[64][32];
    __shared__ float lvx[64][32];
    __shared__ float S[64][65];
    const int xq = blockIdx.x, h = blockIdx.y, b = blockIdx.z;
    const int tid = threadIdx.x;
    const size_t rowx = ((size_t)b * 64 + xq) * 64;   // row base for (b, x, a)
    const int ch = h * 32;

    {   // stage lk[b,x,:,h,:] and lv[b,x,:,h,:] into LDS
        const int a = tid >> 2, d0 = (tid & 3) * 8;
        const float4* p = (const float4*)(lk + (rowx + a) * 256 + ch + d0);
        float4 v0 = p[0], v1 = p[1];
        lkx[a][d0 + 0] = v0.x; lkx[a][d0 + 1] = v0.y; lkx[a][d0 + 2] = v0.z; lkx[a][d0 + 3] = v0.w;
        lkx[a][d0 + 4] = v1.x; lkx[a][d0 + 5] = v1.y; lkx[a][d0 + 6] = v1.z; lkx[a][d0 + 7] = v1.w;
        const float4* q = (const float4*)(lv + (rowx + a) * 256 + ch + d0);
        float4 w0 = q[0], w1 = q[1];
        lvx[a][d0 + 0] = w0.x; lvx[a][d0 + 1] = w0.y; lvx[a][d0 + 2] = w0.z; lvx[a][d0 + 3] = w0.w;
        lvx[a][d0 + 4] = w1.x; lvx[a][d0 + 5] = w1.y; lvx[a][d0 + 6] = w1.z; lvx[a][d0 + 7] = w1.w;
    }
    __syncthreads();

    {   // scores
        const int y = tid & 63, az = tid >> 6;
        for (int a = az; a < 64; a += 4) {
            const float4* rp = (const float4*)(rk + (((size_t)b * 64 + a) * 64 + y) * 256 + ch);
            float acc = 0.f;
            #pragma unroll
            for (int dq = 0; dq < 8; ++dq) {
                float4 r = rp[dq];
                acc += lkx[a][4 * dq + 0] * r.x + lkx[a][4 * dq + 1] * r.y
                     + lkx[a][4 * dq + 2] * r.z + lkx[a][4 * dq + 3] * r.w;
            }
            S[a][y] = acc * 0.17677669529663687f;   // 1/sqrt(32)
        }
    }
    __syncthreads();

    if (tid < 64) {   // softmax over a, per column y
        const int y = tid;
        float mx = -1e30f;
        #pragma unroll 8
        for (int a = 0; a < 64; ++a) mx = fmaxf(mx, S[a][y]);
        float sum = 0.f;
        #pragma unroll 8
        for (int a = 0; a < 64; ++a) { float e = __expf(S[a][y] - mx); S[a][y] = e; sum += e; }
        float inv = 1.f / sum;
        #pragma unroll 8
        for (int a = 0; a < 64; ++a) S[a][y] *= inv;
    }
    __syncthreads();

    {   // aggregation
        const int d = tid & 31, yz = tid >> 5;
        for (int y = yz; y < 64; y += 8) {
            const float* rvp = rv + ((size_t)b * 64 * 64 + y) * 256 + ch + d;
            float acc = 0.f;
            #pragma unroll 8
            for (int a = 0; a < 64; ++a) {
                acc += S[a][y] * lvx[a][d] * rvp[(size_t)a * 64 * 256];
            }
            obuf[(rowx + y) * 256 + ch + d] = acc;
        }
    }
}

// ---------------------------------------------------------------------------
// LN: out = LayerNorm(p + q) * g + b   (row length 256, one block per row)
// ---------------------------------------------------------------------------
__global__ __launch_bounds__(256)
void ln_add(const float* __restrict__ p, const float* __restrict__ q,
            const float* __restrict__ g, const float* __restrict__ be,
            float* __restrict__ out)
{
    const int row = blockIdx.x, tid = threadIdx.x;
    const size_t idx = (size_t)row * 256 + tid;
    float v = p[idx] + q[idx];
    float s = v, qq = v * v;
    #pragma unroll
    for (int off = 32; off > 0; off >>= 1) { s += __shfl_down(s, off); qq += __shfl_down(qq, off); }
    __shared__ float ps[4], pq[4];
    __shared__ float mu_s, ri_s;
    if ((tid & 63) == 0) { ps[tid >> 6] = s; pq[tid >> 6] = qq; }
    __syncthreads();
    if (tid == 0) {
        float S = ps[0] + ps[1] + ps[2] + ps[3];
        float Q = pq[0] + pq[1] + pq[2] + pq[3];
        float mu = S * (1.f / 256.f);
        float var = Q * (1.f / 256.f) - mu * mu;
        mu_s = mu; ri_s = rsqrtf(var + 1e-5f);
    }
    __syncthreads();
    out[idx] = (v - mu_s) * ri_s * g[tid] + be[tid];
}

// ---------------------------------------------------------------------------
extern "C" void kernel_launch(void* const* d_in, const int* in_sizes, int n_in,
                              void* d_out, int out_size, void* d_ws, size_t ws_size,
                              hipStream_t stream)
{
    const float* x    = (const float*)d_in[0];
    const float* Wlk  = (const float*)d_in[1];
    const float* Wrk  = (const float*)d_in[2];
    const float* Wlv  = (const float*)d_in[3];
    const float* Wrv  = (const float*)d_in[4];
    const float* Wout = (const float*)d_in[5];
    const float* g1   = (const float*)d_in[6];
    const float* be1  = (const float*)d_in[7];
    const float* W1   = (const float*)d_in[8];
    const float* b1   = (const float*)d_in[9];
    const float* W2   = (const float*)d_in[10];
    const float* b2   = (const float*)d_in[11];
    const float* g2   = (const float*)d_in[12];
    const float* be2  = (const float*)d_in[13];

    float* ws = (float*)d_ws;
    const size_t M = (size_t)ROWS * DIM;     // 2,097,152 floats per buffer
    float* lk   = ws;                        // [0,   M)
    float* rk   = ws + M;                    // [M,  2M)
    float* lv   = ws + 2 * M;                // [2M, 3M)
    float* rv   = ws + 3 * M;                // [3M, 4M)
    float* obuf = ws + 4 * M;                // [4M, 5M)
    float* tmp1 = ws;                        // reuse lk   (dead after tri_attn)
    float* hbuf = ws + M;                    // reuse rk   (dead after tri_attn)
    float* mid  = ws + 2 * M;                // reuse lv+rv: 8192x512 = 2M floats -> [2M,4M)
    float* tmp2 = ws + 4 * M;                // reuse obuf (dead after out-proj)

    // 1. projections: lk, rk, lv, rv
    proj_gemm<<<dim3(16, 128), 256, 0, stream>>>(x, Wlk, Wrk, Wlv, Wrv, lk);
    // 2. triangle attention -> obuf
    tri_attn<<<dim3(64, 8, 2), 256, 0, stream>>>(lk, rk, lv, rv, obuf);
    // 3. out projection: tmp1 = obuf @ W_out
    gemm_f32<<<dim3(4, 128), 256, 0, stream>>>(obuf, Wout, nullptr, 0, tmp1, 256, 256);
    // 4. h = LN(x + tmp1)
    ln_add<<<8192, 256, 0, stream>>>(x, tmp1, g1, be1, hbuf);
    // 5. mid = relu(h @ W1 + b1)
    gemm_f32<<<dim3(8, 128), 256, 0, stream>>>(hbuf, W1, b1, 1, mid, 256, 512);
    // 6. tmp2 = mid @ W2 + b2
    gemm_f32<<<dim3(4, 128), 256, 0, stream>>>(mid, W2, b2, 0, tmp2, 512, 256);
    // 7. out = LN(tmp2 + h) -> fp32
    ln_add<<<8192, 256, 0, stream>>>(hbuf, tmp2, g2, be2, (float*)d_out);
}

// Round 3
// 200.265 us; speedup vs baseline: 2.0749x; 2.0749x over previous
//
#include <hip/hip_runtime.h>

// B=2, N=64, D=256, H=8, DK=32.  ROWS = B*N*N = 8192.
#define ROWS 8192
#define DIM  256

typedef short short8 __attribute__((ext_vector_type(8)));
typedef float f4     __attribute__((ext_vector_type(4)));

__device__ __forceinline__ float bf2f(unsigned int u16) {
    union { unsigned int i; float f; } v;
    v.i = (u16 & 0xffffu) << 16;
    return v.f;
}
__device__ __forceinline__ unsigned short f2bf(float f) {
    union { float f; unsigned int u; } v; v.f = f;
    unsigned int r = v.u + 0x7fffu + ((v.u >> 16) & 1u);   // RNE
    return (unsigned short)(r >> 16);
}

// ---------------------------------------------------------------------------
// cast x (8192x256 fp32) -> xb bf16 row-major
// ---------------------------------------------------------------------------
__global__ __launch_bounds__(256)
void cast_x(const float* __restrict__ x, unsigned short* __restrict__ xb)
{
    const size_t i = ((size_t)blockIdx.x * 256 + threadIdx.x) * 4;
    float4 v = *(const float4*)(x + i);
    unsigned int lo = f2bf(v.x) | ((unsigned int)f2bf(v.y) << 16);
    unsigned int hi = f2bf(v.z) | ((unsigned int)f2bf(v.w) << 16);
    uint2 p; p.x = lo; p.y = hi;
    *(uint2*)(xb + i) = p;
}

// ---------------------------------------------------------------------------
// cast + transpose all 7 weights into WT[n][k] bf16, packed buffer.
// offsets (elems): w0..w4: w*65536 ; W1(256x512)->WT512x256 @327680 ;
//                  W2(512x256)->WT256x512 @458752
// grid.x = 576 blocks of 256 thr; 32x32 tiles.
// ---------------------------------------------------------------------------
__global__ __launch_bounds__(256)
void cast_w(const float* __restrict__ w0, const float* __restrict__ w1,
            const float* __restrict__ w2, const float* __restrict__ w3,
            const float* __restrict__ w4, const float* __restrict__ w5,
            const float* __restrict__ w6, unsigned short* __restrict__ wt)
{
    __shared__ float t[32][33];
    int id = blockIdx.x;
    const float* src; int K, N, Ntiles; size_t doff;
    if (id < 320) {
        int w = id >> 6; id &= 63; K = 256; N = 256; Ntiles = 8;
        doff = (size_t)w * 65536;
        src = (w == 0) ? w0 : (w == 1) ? w1 : (w == 2) ? w2 : (w == 3) ? w3 : w4;
    } else if (id < 448) {
        id -= 320; K = 256; N = 512; Ntiles = 16; doff = 327680; src = w5;
    } else {
        id -= 448; K = 512; N = 256; Ntiles = 8;  doff = 458752; src = w6;
    }
    const int tk = id / Ntiles, tn = id % Ntiles;
    const int k0 = tk * 32, n0 = tn * 32;
    const int c = threadIdx.x & 31, r8 = threadIdx.x >> 5;
    for (int rr = r8; rr < 32; rr += 8)
        t[rr][c] = src[(size_t)(k0 + rr) * N + n0 + c];
    __syncthreads();
    for (int rr = r8; rr < 32; rr += 8)
        wt[doff + (size_t)(n0 + rr) * K + k0 + c] = f2bf(t[c][rr]);
}

// ---------------------------------------------------------------------------
// Generic MFMA GEMM: out = epilogue( A(Mx K bf16) @ WT(NxK bf16)^T )
// block = 256 thr (4 waves), tile 128x64; wave = 32 rows x 64 cols.
// mode 0: fp32 out.  mode 1: +bias, relu, bf16 out.  mode 2: +bias, fp32 out.
// grid = (N/64, M/128)
// ---------------------------------------------------------------------------
__global__ __launch_bounds__(256)
void gemm_mfma(const unsigned short* __restrict__ A, const unsigned short* __restrict__ WT,
               const float* __restrict__ bias, float* __restrict__ outF,
               unsigned short* __restrict__ outB, int K, int N, int mode)
{
    const int lane = threadIdx.x & 63, wave = threadIdx.x >> 6;
    const int m0 = blockIdx.y * 128 + wave * 32;
    const int col0 = blockIdx.x * 64;
    const int lm = lane & 15, lk8 = (lane >> 4) * 8;

    f4 acc[2][4];
    #pragma unroll
    for (int i = 0; i < 2; ++i)
        #pragma unroll
        for (int j = 0; j < 4; ++j) acc[i][j] = (f4){0.f, 0.f, 0.f, 0.f};

    for (int kc = 0; kc < K; kc += 32) {
        short8 af[2], bf[4];
        #pragma unroll
        for (int i = 0; i < 2; ++i)
            af[i] = *(const short8*)(A + (size_t)(m0 + i * 16 + lm) * K + kc + lk8);
        #pragma unroll
        for (int j = 0; j < 4; ++j)
            bf[j] = *(const short8*)(WT + (size_t)(col0 + j * 16 + lm) * K + kc + lk8);
        #pragma unroll
        for (int i = 0; i < 2; ++i)
            #pragma unroll
            for (int j = 0; j < 4; ++j)
                acc[i][j] = __builtin_amdgcn_mfma_f32_16x16x32_bf16(af[i], bf[j], acc[i][j], 0, 0, 0);
    }

    const int rbase = (lane >> 4) * 4;
    #pragma unroll
    for (int i = 0; i < 2; ++i)
        #pragma unroll
        for (int j = 0; j < 4; ++j) {
            const int n = col0 + j * 16 + lm;
            float bb = (mode >= 1) ? bias[n] : 0.f;
            #pragma unroll
            for (int r = 0; r < 4; ++r) {
                const int m = m0 + i * 16 + rbase + r;
                float v = acc[i][j][r] + bb;
                if (mode == 1) {
                    v = fmaxf(v, 0.f);
                    outB[(size_t)m * N + n] = f2bf(v);
                } else {
                    outF[(size_t)m * N + n] = v;
                }
            }
        }
}

// ---------------------------------------------------------------------------
// Projection MFMA GEMM with head-major scatter epilogue.
// A = xb (8192x256 bf16), WT packed (wsel = blockIdx.x>>2).
// Row m = (b*64+i)*64+j, col c = h*32+d.
//   wsel 0 (lk): dst[b][h][ a=j ][ x=i ][d]
//   wsel 1 (rk): dst[b][h][ a=i ][ y=j ][d]
//   wsel 2 (lv): dst[b][h][ x=i ][ a=j ][d]
//   wsel 3 (rv): dst[b][h][ y=j ][ a=i ][d]
// dstbase = projT + wsel*2097152 (each 2M bf16 elems)
// grid = (16, 64)
// ---------------------------------------------------------------------------
__global__ __launch_bounds__(256)
void proj_mfma(const unsigned short* __restrict__ A, const unsigned short* __restrict__ WT,
               unsigned short* __restrict__ projT)
{
    const int lane = threadIdx.x & 63, wave = threadIdx.x >> 6;
    const int wsel = blockIdx.x >> 2;
    const int col0 = (blockIdx.x & 3) * 64;
    const int m0 = blockIdx.y * 128 + wave * 32;
    const int lm = lane & 15, lk8 = (lane >> 4) * 8;
    const unsigned short* W = WT + (size_t)wsel * 65536;
    unsigned short* dst = projT + (size_t)wsel * 2097152;

    f4 acc[2][4];
    #pragma unroll
    for (int i = 0; i < 2; ++i)
        #pragma unroll
        for (int j = 0; j < 4; ++j) acc[i][j] = (f4){0.f, 0.f, 0.f, 0.f};

    for (int kc = 0; kc < 256; kc += 32) {
        short8 af[2], bf[4];
        #pragma unroll
        for (int i = 0; i < 2; ++i)
            af[i] = *(const short8*)(A + (size_t)(m0 + i * 16 + lm) * 256 + kc + lk8);
        #pragma unroll
        for (int j = 0; j < 4; ++j)
            bf[j] = *(const short8*)(W + (size_t)(col0 + j * 16 + lm) * 256 + kc + lk8);
        #pragma unroll
        for (int i = 0; i < 2; ++i)
            #pragma unroll
            for (int j = 0; j < 4; ++j)
                acc[i][j] = __builtin_amdgcn_mfma_f32_16x16x32_bf16(af[i], bf[j], acc[i][j], 0, 0, 0);
    }

    const int rbase = (lane >> 4) * 4;
    const int swap = (wsel == 0 || wsel == 3);
    #pragma unroll
    for (int i = 0; i < 2; ++i)
        #pragma unroll
        for (int j = 0; j < 4; ++j) {
            const int c = col0 + j * 16 + lm;
            const int h = c >> 5, d = c & 31;
            #pragma unroll
            for (int r = 0; r < 4; ++r) {
                const int m = m0 + i * 16 + rbase + r;
                const int b = m >> 12, ii = (m >> 6) & 63, jj = m & 63;
                const int p = swap ? jj : ii;
                const int q = swap ? ii : jj;
                const size_t idx = ((((size_t)b * 8 + h) * 64 + p) * 64 + q) * 32 + d;
                dst[idx] = f2bf(acc[i][j][r]);
            }
        }
}

// ---------------------------------------------------------------------------
// Scores: per (b,h,a): S_a[x,y] = sum_d lkT[a][x][d] * rkT[a][y][d] / sqrt(32)
// S layout: [b][h][x][a][y] fp32.  grid = 256 blocks (4 a per block, 1/wave).
// ---------------------------------------------------------------------------
__global__ __launch_bounds__(256)
void scores_mfma(const unsigned short* __restrict__ lkT, const unsigned short* __restrict__ rkT,
                 float* __restrict__ S)
{
    const int lane = threadIdx.x & 63, wave = threadIdx.x >> 6;
    const int bi = blockIdx.x;
    const int b = bi >> 7, h = (bi >> 4) & 7, a = (bi & 15) * 4 + wave;
    const size_t bh = (size_t)b * 8 + h;
    const unsigned short* lkb = lkT + (bh * 64 + a) * 2048;   // 64x * 32d
    const unsigned short* rkb = rkT + (bh * 64 + a) * 2048;   // 64y * 32d
    const int lm = lane & 15, lk8 = (lane >> 4) * 8;

    short8 af[4], bf[4];
    #pragma unroll
    for (int t = 0; t < 4; ++t) {
        af[t] = *(const short8*)(lkb + (t * 16 + lm) * 32 + lk8);
        bf[t] = *(const short8*)(rkb + (t * 16 + lm) * 32 + lk8);
    }
    const int rbase = (lane >> 4) * 4;
    float* Sb = S + (bh * 64) * 4096;   // + x*4096 + a*64 + y
    #pragma unroll
    for (int mt = 0; mt < 4; ++mt)
        #pragma unroll
        for (int nt = 0; nt < 4; ++nt) {
            f4 acc = (f4){0.f, 0.f, 0.f, 0.f};
            acc = __builtin_amdgcn_mfma_f32_16x16x32_bf16(af[mt], bf[nt], acc, 0, 0, 0);
            #pragma unroll
            for (int r = 0; r < 4; ++r) {
                const int x = mt * 16 + rbase + r;
                const int y = nt * 16 + lm;
                Sb[(size_t)x * 4096 + a * 64 + y] = acc[r] * 0.17677669529663687f;
            }
        }
}

// ---------------------------------------------------------------------------
// Softmax over a + triple-product aggregation. One block per (b,h,x).
//   att[a,y] = softmax_a(S[b,h,x,a,y]);  o[y,d] = sum_a att*lvT[x][a][d]*rvT[y][a][d]
// obuf_b[(b*64+x)*64+y][h*32+d] bf16.  grid = 1024, 256 thr.
// ---------------------------------------------------------------------------
__global__ __launch_bounds__(256)
void softmax_agg(const float* __restrict__ S, const unsigned short* __restrict__ lvT,
                 const unsigned short* __restrict__ rvT, unsigned short* __restrict__ obuf)
{
    __shared__ float att[64][64];
    __shared__ float lvL[64][32];
    __shared__ float smx[4][64], ssm[4][64], invL[64];
    const int bi = blockIdx.x;
    const int b = bi >> 9, h = (bi >> 6) & 7, x = bi & 63;
    const size_t bh = (size_t)b * 8 + h;
    const int tid = threadIdx.x;

    // phase 1: load S slice + partial max; stage lv
    const float* Sg = S + (bh * 64 + x) * 4096;
    {
        const int y = tid & 63, aq = tid >> 6;
        float mx = -1e30f;
        #pragma unroll
        for (int k = 0; k < 16; ++k) {
            const int a = aq * 16 + k;
            float v = Sg[(size_t)a * 64 + y];
            att[a][y] = v;
            mx = fmaxf(mx, v);
        }
        smx[aq][y] = mx;
    }
    {
        const unsigned short* lvg = lvT + (bh * 64 + x) * 2048;
        const int a = tid >> 2, d0 = (tid & 3) * 8;
        uint4 pk = *(const uint4*)(lvg + a * 32 + d0);
        lvL[a][d0 + 0] = bf2f(pk.x); lvL[a][d0 + 1] = bf2f(pk.x >> 16);
        lvL[a][d0 + 2] = bf2f(pk.y); lvL[a][d0 + 3] = bf2f(pk.y >> 16);
        lvL[a][d0 + 4] = bf2f(pk.z); lvL[a][d0 + 5] = bf2f(pk.z >> 16);
        lvL[a][d0 + 6] = bf2f(pk.w); lvL[a][d0 + 7] = bf2f(pk.w >> 16);
    }
    __syncthreads();

    // phase 2: exp + partial sums
    {
        const int y = tid & 63, aq = tid >> 6;
        const float mx = fmaxf(fmaxf(smx[0][y], smx[1][y]), fmaxf(smx[2][y], smx[3][y]));
        float s = 0.f;
        #pragma unroll
        for (int k = 0; k < 16; ++k) {
            const int a = aq * 16 + k;
            float e = __expf(att[a][y] - mx);
            att[a][y] = e;
            s += e;
        }
        ssm[aq][y] = s;
    }
    __syncthreads();
    if (tid < 64)
        invL[tid] = 1.f / (ssm[0][tid] + ssm[1][tid] + ssm[2][tid] + ssm[3][tid]);
    __syncthreads();

    // phase 3: aggregation. thread = (dp = d-pair, yb); y = yb + 16*iter
    {
        const int dp = tid & 15, yb = tid >> 4;
        #pragma unroll
        for (int it = 0; it < 4; ++it) {
            const int y = yb + it * 16;
            const unsigned short* rvr = rvT + (bh * 64 + y) * 2048 + dp * 2;
            float a0 = 0.f, a1 = 0.f;
            #pragma unroll 8
            for (int a = 0; a < 64; ++a) {
                unsigned int pk = *(const unsigned int*)(rvr + a * 32);
                float w = att[a][y];
                a0 += w * lvL[a][2 * dp]     * bf2f(pk);
                a1 += w * lvL[a][2 * dp + 1] * bf2f(pk >> 16);
            }
            const float inv = invL[y];
            a0 *= inv; a1 *= inv;
            unsigned int st = f2bf(a0) | ((unsigned int)f2bf(a1) << 16);
            *(unsigned int*)(obuf + (((size_t)b * 64 + x) * 64 + y) * 256 + h * 32 + dp * 2) = st;
        }
    }
}

// ---------------------------------------------------------------------------
// LN1: h = LayerNorm(x + t) * g + b  -> hf (fp32) and hb (bf16)
// ---------------------------------------------------------------------------
__global__ __launch_bounds__(256)
void ln1(const float* __restrict__ x, const float* __restrict__ t,
         const float* __restrict__ g, const float* __restrict__ be,
         float* __restrict__ hf, unsigned short* __restrict__ hb)
{
    const int row = blockIdx.x, tid = threadIdx.x;
    const size_t idx = (size_t)row * 256 + tid;
    float v = x[idx] + t[idx];
    float s = v, qq = v * v;
    #pragma unroll
    for (int off = 32; off > 0; off >>= 1) { s += __shfl_down(s, off); qq += __shfl_down(qq, off); }
    __shared__ float ps[4], pq[4];
    __shared__ float mu_s, ri_s;
    if ((tid & 63) == 0) { ps[tid >> 6] = s; pq[tid >> 6] = qq; }
    __syncthreads();
    if (tid == 0) {
        float Sm = ps[0] + ps[1] + ps[2] + ps[3];
        float Q  = pq[0] + pq[1] + pq[2] + pq[3];
        float mu = Sm * (1.f / 256.f);
        float var = Q * (1.f / 256.f) - mu * mu;
        mu_s = mu; ri_s = rsqrtf(var + 1e-5f);
    }
    __syncthreads();
    float r = (v - mu_s) * ri_s * g[tid] + be[tid];
    hf[idx] = r;
    hb[idx] = f2bf(r);
}

// ---------------------------------------------------------------------------
// LN2: out = LayerNorm(hf + t) * g + b  -> fp32
// ---------------------------------------------------------------------------
__global__ __launch_bounds__(256)
void ln2(const float* __restrict__ hf, const float* __restrict__ t,
         const float* __restrict__ g, const float* __restrict__ be,
         float* __restrict__ out)
{
    const int row = blockIdx.x, tid = threadIdx.x;
    const size_t idx = (size_t)row * 256 + tid;
    float v = hf[idx] + t[idx];
    float s = v, qq = v * v;
    #pragma unroll
    for (int off = 32; off > 0; off >>= 1) { s += __shfl_down(s, off); qq += __shfl_down(qq, off); }
    __shared__ float ps[4], pq[4];
    __shared__ float mu_s, ri_s;
    if ((tid & 63) == 0) { ps[tid >> 6] = s; pq[tid >> 6] = qq; }
    __syncthreads();
    if (tid == 0) {
        float Sm = ps[0] + ps[1] + ps[2] + ps[3];
        float Q  = pq[0] + pq[1] + pq[2] + pq[3];
        float mu = Sm * (1.f / 256.f);
        float var = Q * (1.f / 256.f) - mu * mu;
        mu_s = mu; ri_s = rsqrtf(var + 1e-5f);
    }
    __syncthreads();
    out[idx] = (v - mu_s) * ri_s * g[tid] + be[tid];
}

// ---------------------------------------------------------------------------
extern "C" void kernel_launch(void* const* d_in, const int* in_sizes, int n_in,
                              void* d_out, int out_size, void* d_ws, size_t ws_size,
                              hipStream_t stream)
{
    const float* x    = (const float*)d_in[0];
    const float* Wlk  = (const float*)d_in[1];
    const float* Wrk  = (const float*)d_in[2];
    const float* Wlv  = (const float*)d_in[3];
    const float* Wrv  = (const float*)d_in[4];
    const float* Wout = (const float*)d_in[5];
    const float* g1   = (const float*)d_in[6];
    const float* be1  = (const float*)d_in[7];
    const float* W1   = (const float*)d_in[8];
    const float* b1   = (const float*)d_in[9];
    const float* W2   = (const float*)d_in[10];
    const float* b2   = (const float*)d_in[11];
    const float* g2   = (const float*)d_in[12];
    const float* be2  = (const float*)d_in[13];

    char* base = (char*)d_ws;
    const size_t MB = 1ull << 20;
    unsigned short* xb    = (unsigned short*)(base + 0);        // 4MB; reused as obuf
    unsigned short* obufb = (unsigned short*)(base + 0);
    unsigned short* projT = (unsigned short*)(base + 4 * MB);   // lkT,rkT,lvT,rvT 4x4MB
    unsigned short* lkT   = projT;
    unsigned short* rkT   = projT + 2097152;
    unsigned short* lvT   = projT + 2 * 2097152;
    unsigned short* rvT   = projT + 3 * 2097152;
    float*          S     = (float*)(base + 20 * MB);           // 16MB; reused as tmp1
    float*          tmp1  = (float*)(base + 20 * MB);           // 8MB
    float*          hbuf  = (float*)(base + 4 * MB);            // 8MB (over lkT+rkT)
    unsigned short* hb    = (unsigned short*)(base + 12 * MB);  // 4MB (over lvT)
    unsigned short* midb  = (unsigned short*)(base + 36 * MB);  // 8MB
    float*          tmp2  = (float*)(base + 44 * MB);           // 8MB
    unsigned short* WT    = (unsigned short*)(base + 52 * MB);  // 1.2MB

    // 0. casts
    cast_x<<<2048, 256, 0, stream>>>(x, xb);
    cast_w<<<576, 256, 0, stream>>>(Wlk, Wrk, Wlv, Wrv, Wout, W1, W2, WT);
    // 1. projections + head-major scatter
    proj_mfma<<<dim3(16, 64), 256, 0, stream>>>(xb, WT, projT);
    // 2. scores (MFMA) -> S
    scores_mfma<<<256, 256, 0, stream>>>(lkT, rkT, S);
    // 3. softmax + aggregation -> obuf_b (bf16)
    softmax_agg<<<1024, 256, 0, stream>>>(S, lvT, rvT, obufb);
    // 4. out projection: tmp1 = obuf @ W_out (fp32 out)
    gemm_mfma<<<dim3(4, 64), 256, 0, stream>>>(obufb, WT + 262144, nullptr, tmp1, nullptr, 256, 256, 0);
    // 5. h = LN(x + tmp1) -> hbuf (fp32) + hb (bf16)
    ln1<<<8192, 256, 0, stream>>>(x, tmp1, g1, be1, hbuf, hb);
    // 6. midb = relu(h @ W1 + b1) (bf16 out)
    gemm_mfma<<<dim3(8, 64), 256, 0, stream>>>(hb, WT + 327680, b1, nullptr, midb, 256, 512, 1);
    // 7. tmp2 = midb @ W2 + b2 (fp32 out)
    gemm_mfma<<<dim3(4, 64), 256, 0, stream>>>(midb, WT + 458752, b2, tmp2, nullptr, 512, 256, 2);
    // 8. out = LN(hbuf + tmp2)
    ln2<<<8192, 256, 0, stream>>>(hbuf, tmp2, g2, be2, (float*)d_out);
}

// Round 4
// 199.500 us; speedup vs baseline: 2.0829x; 1.0038x over previous
//
#include <hip/hip_runtime.h>

// B=2, N=64, D=256, H=8, DK=32.  ROWS = B*N*N = 8192.
#define ROWS 8192
#define DIM  256

typedef short short8 __attribute__((ext_vector_type(8)));
typedef float f4     __attribute__((ext_vector_type(4)));

__device__ __forceinline__ float bf2f(unsigned int u16) {
    union { unsigned int i; float f; } v;
    v.i = (u16 & 0xffffu) << 16;
    return v.f;
}
__device__ __forceinline__ unsigned short f2bf(float f) {
    union { float f; unsigned int u; } v; v.f = f;
    unsigned int r = v.u + 0x7fffu + ((v.u >> 16) & 1u);   // RNE
    return (unsigned short)(r >> 16);
}

// ---------------------------------------------------------------------------
// cast x (8192x256 fp32) -> xb bf16 row-major
// ---------------------------------------------------------------------------
__global__ __launch_bounds__(256)
void cast_x(const float* __restrict__ x, unsigned short* __restrict__ xb)
{
    const size_t i = ((size_t)blockIdx.x * 256 + threadIdx.x) * 4;
    float4 v = *(const float4*)(x + i);
    unsigned int lo = f2bf(v.x) | ((unsigned int)f2bf(v.y) << 16);
    unsigned int hi = f2bf(v.z) | ((unsigned int)f2bf(v.w) << 16);
    uint2 p; p.x = lo; p.y = hi;
    *(uint2*)(xb + i) = p;
}

// ---------------------------------------------------------------------------
// cast + transpose all 7 weights into WT[n][k] bf16, packed buffer.
// offsets (elems): w0..w4: w*65536 ; W1(256x512)->WT512x256 @327680 ;
//                  W2(512x256)->WT256x512 @458752
// ---------------------------------------------------------------------------
__global__ __launch_bounds__(256)
void cast_w(const float* __restrict__ w0, const float* __restrict__ w1,
            const float* __restrict__ w2, const float* __restrict__ w3,
            const float* __restrict__ w4, const float* __restrict__ w5,
            const float* __restrict__ w6, unsigned short* __restrict__ wt)
{
    __shared__ float t[32][33];
    int id = blockIdx.x;
    const float* src; int K, N, Ntiles; size_t doff;
    if (id < 320) {
        int w = id >> 6; id &= 63; K = 256; N = 256; Ntiles = 8;
        doff = (size_t)w * 65536;
        src = (w == 0) ? w0 : (w == 1) ? w1 : (w == 2) ? w2 : (w == 3) ? w3 : w4;
    } else if (id < 448) {
        id -= 320; K = 256; N = 512; Ntiles = 16; doff = 327680; src = w5;
    } else {
        id -= 448; K = 512; N = 256; Ntiles = 8;  doff = 458752; src = w6;
    }
    const int tk = id / Ntiles, tn = id % Ntiles;
    const int k0 = tk * 32, n0 = tn * 32;
    const int c = threadIdx.x & 31, r8 = threadIdx.x >> 5;
    for (int rr = r8; rr < 32; rr += 8)
        t[rr][c] = src[(size_t)(k0 + rr) * N + n0 + c];
    __syncthreads();
    for (int rr = r8; rr < 32; rr += 8)
        wt[doff + (size_t)(n0 + rr) * K + k0 + c] = f2bf(t[c][rr]);
}

// ---------------------------------------------------------------------------
// Generic MFMA GEMM: out = epilogue( A(MxK bf16) @ WT(NxK bf16)^T )
// block = 256 thr (4 waves), tile 128x64; wave = 32 rows x 64 cols.
// mode 0: fp32 out.  mode 1: +bias, relu, bf16 out.  mode 2: +bias, fp32 out.
// grid = (N/64, M/128)
// ---------------------------------------------------------------------------
__global__ __launch_bounds__(256)
void gemm_mfma(const unsigned short* __restrict__ A, const unsigned short* __restrict__ WT,
               const float* __restrict__ bias, float* __restrict__ outF,
               unsigned short* __restrict__ outB, int K, int N, int mode)
{
    const int lane = threadIdx.x & 63, wave = threadIdx.x >> 6;
    const int m0 = blockIdx.y * 128 + wave * 32;
    const int col0 = blockIdx.x * 64;
    const int lm = lane & 15, lk8 = (lane >> 4) * 8;

    f4 acc[2][4];
    #pragma unroll
    for (int i = 0; i < 2; ++i)
        #pragma unroll
        for (int j = 0; j < 4; ++j) acc[i][j] = (f4){0.f, 0.f, 0.f, 0.f};

    for (int kc = 0; kc < K; kc += 32) {
        short8 af[2], bf[4];
        #pragma unroll
        for (int i = 0; i < 2; ++i)
            af[i] = *(const short8*)(A + (size_t)(m0 + i * 16 + lm) * K + kc + lk8);
        #pragma unroll
        for (int j = 0; j < 4; ++j)
            bf[j] = *(const short8*)(WT + (size_t)(col0 + j * 16 + lm) * K + kc + lk8);
        #pragma unroll
        for (int i = 0; i < 2; ++i)
            #pragma unroll
            for (int j = 0; j < 4; ++j)
                acc[i][j] = __builtin_amdgcn_mfma_f32_16x16x32_bf16(af[i], bf[j], acc[i][j], 0, 0, 0);
    }

    const int rbase = (lane >> 4) * 4;
    #pragma unroll
    for (int i = 0; i < 2; ++i)
        #pragma unroll
        for (int j = 0; j < 4; ++j) {
            const int n = col0 + j * 16 + lm;
            float bb = (mode >= 1) ? bias[n] : 0.f;
            #pragma unroll
            for (int r = 0; r < 4; ++r) {
                const int m = m0 + i * 16 + rbase + r;
                float v = acc[i][j][r] + bb;
                if (mode == 1) {
                    v = fmaxf(v, 0.f);
                    outB[(size_t)m * N + n] = f2bf(v);
                } else {
                    outF[(size_t)m * N + n] = v;
                }
            }
        }
}

// ---------------------------------------------------------------------------
// Projection MFMA GEMM with head-major scatter epilogue.
// A = xb (8192x256 bf16), WT packed (wsel = blockIdx.x>>2).
// Row m = (b*64+i)*64+j, col c = h*32+d.
//   wsel 0 (lk): dst[b][h][ x=i ][ a=j ][d]
//   wsel 1 (rk): dst[b][h][ a=i ][ y=j ][d]
//   wsel 2 (lv): dst[b][h][ x=i ][ a=j ][d]
//   wsel 3 (rv): dst[b][h][ y=j ][ a=i ][d]
// grid = (16, 64)
// ---------------------------------------------------------------------------
__global__ __launch_bounds__(256)
void proj_mfma(const unsigned short* __restrict__ A, const unsigned short* __restrict__ WT,
               unsigned short* __restrict__ projT)
{
    const int lane = threadIdx.x & 63, wave = threadIdx.x >> 6;
    const int wsel = blockIdx.x >> 2;
    const int col0 = (blockIdx.x & 3) * 64;
    const int m0 = blockIdx.y * 128 + wave * 32;
    const int lm = lane & 15, lk8 = (lane >> 4) * 8;
    const unsigned short* W = WT + (size_t)wsel * 65536;
    unsigned short* dst = projT + (size_t)wsel * 2097152;

    f4 acc[2][4];
    #pragma unroll
    for (int i = 0; i < 2; ++i)
        #pragma unroll
        for (int j = 0; j < 4; ++j) acc[i][j] = (f4){0.f, 0.f, 0.f, 0.f};

    for (int kc = 0; kc < 256; kc += 32) {
        short8 af[2], bf[4];
        #pragma unroll
        for (int i = 0; i < 2; ++i)
            af[i] = *(const short8*)(A + (size_t)(m0 + i * 16 + lm) * 256 + kc + lk8);
        #pragma unroll
        for (int j = 0; j < 4; ++j)
            bf[j] = *(const short8*)(W + (size_t)(col0 + j * 16 + lm) * 256 + kc + lk8);
        #pragma unroll
        for (int i = 0; i < 2; ++i)
            #pragma unroll
            for (int j = 0; j < 4; ++j)
                acc[i][j] = __builtin_amdgcn_mfma_f32_16x16x32_bf16(af[i], bf[j], acc[i][j], 0, 0, 0);
    }

    const int rbase = (lane >> 4) * 4;
    const int swap = (wsel == 3);   // only rv stores [y][a]; lk/lv store [x][a], rk [a][y]
    #pragma unroll
    for (int i = 0; i < 2; ++i)
        #pragma unroll
        for (int j = 0; j < 4; ++j) {
            const int c = col0 + j * 16 + lm;
            const int h = c >> 5, d = c & 31;
            #pragma unroll
            for (int r = 0; r < 4; ++r) {
                const int m = m0 + i * 16 + rbase + r;
                const int b = m >> 12, ii = (m >> 6) & 63, jj = m & 63;
                const int p = swap ? jj : ii;
                const int q = swap ? ii : jj;
                const size_t idx = ((((size_t)b * 8 + h) * 64 + p) * 64 + q) * 32 + d;
                dst[idx] = f2bf(acc[i][j][r]);
            }
        }
}

// ---------------------------------------------------------------------------
// Fused triangle attention: scores + softmax + aggregation.
// One block per (b,h,x), 256 thr.
//   S[a,y] = lk[x,a,:]·rk[a,y,:] / sqrt(32);  att = softmax_a(S)
//   o[y,d] = (1/L_y) sum_a att[a,y]*lv[x,a,d]*rv[a,y,d]
// lkT/lvT: [b][h][x][a][d], rkT: [b][h][a][y][d], rvT: [b][h][y][a][d] (bf16)
// obuf[(b*64+x)*64+y][h*32+d] bf16.  grid = 1024.
// ---------------------------------------------------------------------------
__global__ __launch_bounds__(256)
void attn_fused(const unsigned short* __restrict__ lkT, const unsigned short* __restrict__ rkT,
                const unsigned short* __restrict__ lvT, const unsigned short* __restrict__ rvT,
                unsigned short* __restrict__ obuf)
{
    __shared__ float att[64][64];           // [a][y]
    __shared__ float lkx[64][32];           // lk[x,:,:]
    __shared__ float lvL[64][32];           // lv[x,:,:]
    __shared__ float smx[4][64], ssm[4][64], invL[64];
    const int bi = blockIdx.x;
    const int b = bi >> 9, h = (bi >> 6) & 7, x = bi & 63;
    const size_t bh = (size_t)b * 8 + h;
    const int tid = threadIdx.x;

    {   // stage lk[x] and lv[x] (contiguous 4KB each)
        const int a = tid >> 2, d0 = (tid & 3) * 8;
        const size_t off = ((bh * 64 + x) * 64 + a) * 32 + d0;
        uint4 pk = *(const uint4*)(lkT + off);
        lkx[a][d0 + 0] = bf2f(pk.x); lkx[a][d0 + 1] = bf2f(pk.x >> 16);
        lkx[a][d0 + 2] = bf2f(pk.y); lkx[a][d0 + 3] = bf2f(pk.y >> 16);
        lkx[a][d0 + 4] = bf2f(pk.z); lkx[a][d0 + 5] = bf2f(pk.z >> 16);
        lkx[a][d0 + 6] = bf2f(pk.w); lkx[a][d0 + 7] = bf2f(pk.w >> 16);
        uint4 qk = *(const uint4*)(lvT + off);
        lvL[a][d0 + 0] = bf2f(qk.x); lvL[a][d0 + 1] = bf2f(qk.x >> 16);
        lvL[a][d0 + 2] = bf2f(qk.y); lvL[a][d0 + 3] = bf2f(qk.y >> 16);
        lvL[a][d0 + 4] = bf2f(qk.z); lvL[a][d0 + 5] = bf2f(qk.z >> 16);
        lvL[a][d0 + 6] = bf2f(qk.w); lvL[a][d0 + 7] = bf2f(qk.w >> 16);
    }
    __syncthreads();

    {   // scores + per-slice max; thread = (y, az), a = az + 4k
        const int y = tid & 63, az = tid >> 6;
        float mx = -1e30f;
        for (int a = az; a < 64; a += 4) {
            const unsigned short* rp = rkT + ((bh * 64 + a) * 64 + y) * 32;
            float acc = 0.f;
            #pragma unroll
            for (int t = 0; t < 4; ++t) {
                uint4 pk = *(const uint4*)(rp + t * 8);
                acc += lkx[a][t*8 + 0] * bf2f(pk.x) + lkx[a][t*8 + 1] * bf2f(pk.x >> 16)
                     + lkx[a][t*8 + 2] * bf2f(pk.y) + lkx[a][t*8 + 3] * bf2f(pk.y >> 16)
                     + lkx[a][t*8 + 4] * bf2f(pk.z) + lkx[a][t*8 + 5] * bf2f(pk.z >> 16)
                     + lkx[a][t*8 + 6] * bf2f(pk.w) + lkx[a][t*8 + 7] * bf2f(pk.w >> 16);
            }
            float v = acc * 0.17677669529663687f;   // 1/sqrt(32)
            att[a][y] = v;
            mx = fmaxf(mx, v);
        }
        smx[az][y] = mx;
    }
    __syncthreads();

    {   // exp + partial sums
        const int y = tid & 63, az = tid >> 6;
        const float mx = fmaxf(fmaxf(smx[0][y], smx[1][y]), fmaxf(smx[2][y], smx[3][y]));
        float s = 0.f;
        for (int a = az; a < 64; a += 4) {
            float e = __expf(att[a][y] - mx);
            att[a][y] = e;
            s += e;
        }
        ssm[az][y] = s;
    }
    __syncthreads();
    if (tid < 64)
        invL[tid] = 1.f / (ssm[0][tid] + ssm[1][tid] + ssm[2][tid] + ssm[3][tid]);
    __syncthreads();

    {   // aggregation; thread = (dp, yb); y = yb + 16*it
        const int dp = tid & 15, yb = tid >> 4;
        #pragma unroll
        for (int it = 0; it < 4; ++it) {
            const int y = yb + it * 16;
            const unsigned short* rvr = rvT + (bh * 64 + y) * 2048 + dp * 2;
            float a0 = 0.f, a1 = 0.f;
            #pragma unroll 8
            for (int a = 0; a < 64; ++a) {
                unsigned int pk = *(const unsigned int*)(rvr + a * 32);
                float w = att[a][y];
                a0 += w * lvL[a][2 * dp]     * bf2f(pk);
                a1 += w * lvL[a][2 * dp + 1] * bf2f(pk >> 16);
            }
            const float inv = invL[y];
            a0 *= inv; a1 *= inv;
            unsigned int st = f2bf(a0) | ((unsigned int)f2bf(a1) << 16);
            *(unsigned int*)(obuf + (((size_t)b * 64 + x) * 64 + y) * 256 + h * 32 + dp * 2) = st;
        }
    }
}

// ---------------------------------------------------------------------------
// LN1: h = LayerNorm(x + t) * g + b -> hf (fp32) + hb (bf16).
// One wave per row (64 lanes x float4), 4 rows/block. grid = 2048.
// ---------------------------------------------------------------------------
__global__ __launch_bounds__(256)
void ln1(const float* __restrict__ x, const float* __restrict__ t,
         const float* __restrict__ g, const float* __restrict__ be,
         float* __restrict__ hf, unsigned short* __restrict__ hb)
{
    const int wave = threadIdx.x >> 6, lane = threadIdx.x & 63;
    const int row = blockIdx.x * 4 + wave;
    const size_t idx = (size_t)row * 256 + lane * 4;
    float4 a = *(const float4*)(x + idx);
    float4 c = *(const float4*)(t + idx);
    float v0 = a.x + c.x, v1 = a.y + c.y, v2 = a.z + c.z, v3 = a.w + c.w;
    float s = v0 + v1 + v2 + v3;
    float q = v0*v0 + v1*v1 + v2*v2 + v3*v3;
    #pragma unroll
    for (int off = 32; off > 0; off >>= 1) { s += __shfl_down(s, off); q += __shfl_down(q, off); }
    s = __shfl(s, 0); q = __shfl(q, 0);
    const float mu = s * (1.f / 256.f);
    const float ri = rsqrtf(q * (1.f / 256.f) - mu * mu + 1e-5f);
    float4 gg = *(const float4*)(g + lane * 4);
    float4 bb = *(const float4*)(be + lane * 4);
    float4 r;
    r.x = (v0 - mu) * ri * gg.x + bb.x;
    r.y = (v1 - mu) * ri * gg.y + bb.y;
    r.z = (v2 - mu) * ri * gg.z + bb.z;
    r.w = (v3 - mu) * ri * gg.w + bb.w;
    *(float4*)(hf + idx) = r;
    uint2 p;
    p.x = f2bf(r.x) | ((unsigned int)f2bf(r.y) << 16);
    p.y = f2bf(r.z) | ((unsigned int)f2bf(r.w) << 16);
    *(uint2*)(hb + idx) = p;
}

// ---------------------------------------------------------------------------
// LN2: out = LayerNorm(hf + t) * g + b -> fp32. Same structure as ln1.
// ---------------------------------------------------------------------------
__global__ __launch_bounds__(256)
void ln2(const float* __restrict__ hf, const float* __restrict__ t,
         const float* __restrict__ g, const float* __restrict__ be,
         float* __restrict__ out)
{
    const int wave = threadIdx.x >> 6, lane = threadIdx.x & 63;
    const int row = blockIdx.x * 4 + wave;
    const size_t idx = (size_t)row * 256 + lane * 4;
    float4 a = *(const float4*)(hf + idx);
    float4 c = *(const float4*)(t + idx);
    float v0 = a.x + c.x, v1 = a.y + c.y, v2 = a.z + c.z, v3 = a.w + c.w;
    float s = v0 + v1 + v2 + v3;
    float q = v0*v0 + v1*v1 + v2*v2 + v3*v3;
    #pragma unroll
    for (int off = 32; off > 0; off >>= 1) { s += __shfl_down(s, off); q += __shfl_down(q, off); }
    s = __shfl(s, 0); q = __shfl(q, 0);
    const float mu = s * (1.f / 256.f);
    const float ri = rsqrtf(q * (1.f / 256.f) - mu * mu + 1e-5f);
    float4 gg = *(const float4*)(g + lane * 4);
    float4 bb = *(const float4*)(be + lane * 4);
    float4 r;
    r.x = (v0 - mu) * ri * gg.x + bb.x;
    r.y = (v1 - mu) * ri * gg.y + bb.y;
    r.z = (v2 - mu) * ri * gg.z + bb.z;
    r.w = (v3 - mu) * ri * gg.w + bb.w;
    *(float4*)(out + idx) = r;
}

// ---------------------------------------------------------------------------
extern "C" void kernel_launch(void* const* d_in, const int* in_sizes, int n_in,
                              void* d_out, int out_size, void* d_ws, size_t ws_size,
                              hipStream_t stream)
{
    const float* x    = (const float*)d_in[0];
    const float* Wlk  = (const float*)d_in[1];
    const float* Wrk  = (const float*)d_in[2];
    const float* Wlv  = (const float*)d_in[3];
    const float* Wrv  = (const float*)d_in[4];
    const float* Wout = (const float*)d_in[5];
    const float* g1   = (const float*)d_in[6];
    const float* be1  = (const float*)d_in[7];
    const float* W1   = (const float*)d_in[8];
    const float* b1   = (const float*)d_in[9];
    const float* W2   = (const float*)d_in[10];
    const float* b2   = (const float*)d_in[11];
    const float* g2   = (const float*)d_in[12];
    const float* be2  = (const float*)d_in[13];

    char* base = (char*)d_ws;
    const size_t MB = 1ull << 20;
    unsigned short* xb    = (unsigned short*)(base + 0);        // 4MB; reused as obuf
    unsigned short* obufb = (unsigned short*)(base + 0);
    unsigned short* projT = (unsigned short*)(base + 4 * MB);   // lkT,rkT,lvT,rvT 4x4MB
    unsigned short* lkT   = projT;
    unsigned short* rkT   = projT + 2097152;
    unsigned short* lvT   = projT + 2 * 2097152;
    unsigned short* rvT   = projT + 3 * 2097152;
    float*          tmp1  = (float*)(base + 20 * MB);           // 8MB
    float*          hbuf  = (float*)(base + 4 * MB);            // 8MB (over lkT+rkT, dead)
    unsigned short* hb    = (unsigned short*)(base + 12 * MB);  // 4MB (over lvT, dead)
    unsigned short* midb  = (unsigned short*)(base + 36 * MB);  // 8MB
    float*          tmp2  = (float*)(base + 44 * MB);           // 8MB
    unsigned short* WT    = (unsigned short*)(base + 52 * MB);  // 1.2MB

    // 0. casts
    cast_x<<<2048, 256, 0, stream>>>(x, xb);
    cast_w<<<576, 256, 0, stream>>>(Wlk, Wrk, Wlv, Wrv, Wout, W1, W2, WT);
    // 1. projections + head-major scatter
    proj_mfma<<<dim3(16, 64), 256, 0, stream>>>(xb, WT, projT);
    // 2. fused scores+softmax+aggregation -> obuf (bf16)
    attn_fused<<<1024, 256, 0, stream>>>(lkT, rkT, lvT, rvT, obufb);
    // 3. out projection: tmp1 = obuf @ W_out (fp32 out)
    gemm_mfma<<<dim3(4, 64), 256, 0, stream>>>(obufb, WT + 262144, nullptr, tmp1, nullptr, 256, 256, 0);
    // 4. h = LN(x + tmp1) -> hbuf (fp32) + hb (bf16)
    ln1<<<2048, 256, 0, stream>>>(x, tmp1, g1, be1, hbuf, hb);
    // 5. midb = relu(h @ W1 + b1) (bf16 out)
    gemm_mfma<<<dim3(8, 64), 256, 0, stream>>>(hb, WT + 327680, b1, nullptr, midb, 256, 512, 1);
    // 6. tmp2 = midb @ W2 + b2 (fp32 out)
    gemm_mfma<<<dim3(4, 64), 256, 0, stream>>>(midb, WT + 458752, b2, tmp2, nullptr, 512, 256, 2);
    // 7. out = LN(hbuf + tmp2)
    ln2<<<2048, 256, 0, stream>>>(hbuf, tmp2, g2, be2, (float*)d_out);
}